// Round 8
// baseline (234.505 us; speedup 1.0000x reference)
//
#include <hip/hip_runtime.h>

// Problem constants (fixed by reference setup_inputs)
#define N_ROWS   65536      // 32*2048 flattened rows
#define D        256        // embedding_dim
#define D4       64         // D/4 in float4 units
#define M        1024       // n_embeddings
#define LOSS_OFF 16777216   // d_out offset of loss scalar
#define IDX_OFF  16777217   // d_out offset of indices (as float)
#define COMMIT_SCALE (0.25f / 16777216.0f)  // COMMITMENT_COST / numel(x)
#define E_SCALE  1024.0f    // exact pow2 pre-scale of e so e' in [-1,1]
#define C_SCALE  0.001953125f  // 2/1024: acc*C_SCALE == 2*C exactly

typedef _Float16 f16x8 __attribute__((ext_vector_type(8)));
typedef _Float16 f16x4 __attribute__((ext_vector_type(4)));
typedef float    f32x4 __attribute__((ext_vector_type(4)));

// Async global->LDS DMA, 16 B/lane: LDS dest = base + lane*16 (HW-implicit).
__device__ __forceinline__ void async_copy16(const void* g, void* l) {
    __builtin_amdgcn_global_load_lds(
        (const __attribute__((address_space(1))) unsigned int*)g,
        (__attribute__((address_space(3))) unsigned int*)l, 16, 0, 0);
}

// ===== numpy-exact fp32 row-norm emulation (validated rounds 2-3) =========
__device__ __forceinline__ float np_block128(const float* __restrict__ a, int l) {
    float r0 = __fmul_rn(a[l +   0], a[l +   0]);
    float r1 = __fmul_rn(a[l +  16], a[l +  16]);
    float r2 = __fmul_rn(a[l +  32], a[l +  32]);
    float r3 = __fmul_rn(a[l +  48], a[l +  48]);
    float r4 = __fmul_rn(a[l +  64], a[l +  64]);
    float r5 = __fmul_rn(a[l +  80], a[l +  80]);
    float r6 = __fmul_rn(a[l +  96], a[l +  96]);
    float r7 = __fmul_rn(a[l + 112], a[l + 112]);
    return __fadd_rn(__fadd_rn(__fadd_rn(r0, r1), __fadd_rn(r2, r3)),
                     __fadd_rn(__fadd_rn(r4, r5), __fadd_rn(r6, r7)));
}
__device__ __forceinline__ float np_reduce16(float v) {
    float s = __fadd_rn(v, __shfl_down(v, 8));
    s = __fadd_rn(s, __shfl_down(s, 4));
    s = __fadd_rn(s, __shfl_down(s, 2));
    s = __fadd_rn(s, __shfl_down(s, 1));
    return s;
}

// ------- kernel 1: np-exact row norms + (emb branch) fused e-split -------
// (unchanged from rounds 5-7 -- validated absmax 0)
__global__ __launch_bounds__(256) void norms_kernel(
    const float4* __restrict__ x4, const float4* __restrict__ emb4,
    float* __restrict__ bsq, float* __restrict__ esq,
    _Float16* __restrict__ e_hi, _Float16* __restrict__ e_mid,
    float* __restrict__ loss_slot) {
    __shared__ float rowbuf[16 * 260];   // stride 260: conflict-free np reads
    const int tid = threadIdx.x;
    const float4* src4;
    float* dst;
    int row0;
    const bool is_emb = blockIdx.x >= 4096;
    if (!is_emb) {
        row0 = blockIdx.x * 16;
        src4 = x4 + (size_t)row0 * 64;
        dst = bsq + row0;
    } else {
        row0 = (blockIdx.x - 4096) * 16;
        src4 = emb4 + (size_t)row0 * 64;
        dst = esq + row0;
    }
    #pragma unroll
    for (int p = 0; p < 4; ++p) {
        const int f = tid + p * 256;     // 0..1023 float4s = 16 rows
        const int r = f >> 6, c4 = f & 63;
        *(float4*)&rowbuf[r * 260 + c4 * 4] = src4[f];
    }
    __syncthreads();
    const int l = tid & 15, g = tid >> 4;
    const float* base = &rowbuf[g * 260];
    const float v0 = np_block128(base, l);
    const float v1 = np_block128(base + 128, l);
    const float t0 = np_reduce16(v0);
    const float t1 = np_reduce16(v1);
    if (l == 0) dst[g] = __fadd_rn(t0, t1);
    if (blockIdx.x == 0 && tid == 0) *loss_slot = 0.0f;  // d_out is poisoned

    if (is_emb) {
        // Fused esplit: 4 float4s per thread, values from rowbuf (exact).
        #pragma unroll
        for (int p = 0; p < 4; ++p) {
            const int f = tid + p * 256;            // block-local float4 id
            const int r = f >> 6, k4 = f & 63;
            const int code = row0 + r;
            const int kc = k4 >> 3, k8 = k4 & 7;    // 32-k chunk, octet pos
            const int q = k8 >> 1, half = k8 & 1;   // k-octet, half-granule
            const int jt = code >> 7, cl = code & 127;
            const int cg = cl >> 4, lmc = cl & 15;
            float4 v = *(const float4*)&rowbuf[r * 260 + k4 * 4];
            float a[4] = {v.x * E_SCALE, v.y * E_SCALE,
                          v.z * E_SCALE, v.w * E_SCALE};
            f16x4 hi, mid;
            #pragma unroll
            for (int j = 0; j < 4; ++j) {
                _Float16 h = (_Float16)a[j];
                float rr = __fsub_rn(a[j], (float)h);
                hi[j] = h;
                mid[j] = (_Float16)rr;
            }
            const size_t ofs = (size_t)kc * 32768 + (size_t)jt * 4096
                             + (size_t)(cg * 64 + q * 16 + lmc) * 8 + half * 4;
            *(f16x4*)&e_hi[ofs]  = hi;
            *(f16x4*)&e_mid[ofs] = mid;
        }
    }
}

// ---------------- kernel 2: fp16-split MFMA distances + argmin ------------
// Block: 64 rows x all 1024 codes; 4 waves 2x2 (wave = 32 rows x 64 codes).
// Structure = r7 (2-chunk groups, cooperative dedup'd DMA, one fused
// vmcnt(0)+lgkmcnt(0)+s_barrier per group).  NEW (this round): the
// per-sub-chunk hand-written lgkmcnt(0) / sched_barrier(0) / setprio fences
// are REMOVED.  Those fences exist for inline-asm ds_reads (rule 18); our
// B-fragment reads are plain compiler-visible loads, so hipcc inserts its
// own fine-grained lgkmcnt(N) (m97 behavior), starts the MFMA burst as soon
// as the first fragments land, and hoists sub-1 reads under sub-0 MFMAs.
// The old fences forced 8-read-issue -> full-drain -> MFMA lockstep per
// sub-chunk (the measured ~1280 cyc/chunk non-MFMA residue at MfmaUtil 38%).
// Register headroom for hoisted frags: __launch_bounds__(256,2) = 256 regs.
// Fragment bytes + MFMA order (hi*bh, mid*bh, hi*bm; fn inner, kc ascending,
// jt ascending) BIT-IDENTICAL to validated rounds -> absmax 0 preserved.
__global__ __launch_bounds__(256, 2) void argmin_mfma_kernel(
    const float* __restrict__ x,
    const _Float16* __restrict__ e_hi, const _Float16* __restrict__ e_mid,
    const float* __restrict__ esq, const float* __restrict__ bsq,
    float* __restrict__ idx_out_f, int* __restrict__ idx_out_i) {
    // buf[s]: one 2-chunk group: sub*8192 + plane*4096 + data (f16 units);
    // within (sub,plane): granule-permuted chunk half, lane-linear reads.
    __shared__ __attribute__((aligned(16))) _Float16 buf[2][16384];
    __shared__ float esq_lds[1024];
    __shared__ float red_d[64][2];
    __shared__ int   red_i[64][2];

    const int tid = threadIdx.x;
    const int w = tid >> 6, lane = tid & 63;
    const int w_row = w >> 1, w_col = w & 1;
    const int lm = lane & 15, q = lane >> 4;     // A/B frag: [lm][k=q*8+j]
    const int row0 = blockIdx.x * 64;

    // Cooperative group DMA: group g = chunks (jt, kc0) and (jt, kc0+1),
    // 32 KB total.  Wave w moves piece (sub = w>>1, plane = w&1): 8 KB via
    // 8 width-16 ops.  No wave fetches any byte another wave fetches.
    const int p_sub = w >> 1, p_plane = w & 1;
    const _Float16* p_src = p_plane ? e_mid : e_hi;
    auto dma_group = [&](int g, int s) {
        const int jt = g >> 2, kc0 = (g & 3) * 2;
        const char* gp = (const char*)p_src
                       + (size_t)(kc0 + p_sub) * 65536 + (size_t)jt * 8192
                       + (size_t)lane * 16;
        _Float16* lp = &buf[s][p_sub * 8192 + p_plane * 4096];
        #pragma unroll
        for (int u = 0; u < 8; ++u)
            async_copy16(gp + u * 1024, lp + u * 512);
    };

    // Group 0 DMA first: its latency hides under the long A-frag prologue.
    dma_group(0, 0);

    // ---- A fragments: rows row0 + w_row*32 + fm*16 + lm, split on the fly
    f16x8 a_hi[2][8], a_mid[2][8];
    #pragma unroll
    for (int fm = 0; fm < 2; ++fm) {
        const float* xr = x + (size_t)(row0 + w_row * 32 + fm * 16 + lm) * D + q * 8;
        #pragma unroll
        for (int kc = 0; kc < 8; ++kc) {
            float4 v0 = *(const float4*)(xr + kc * 32);
            float4 v1 = *(const float4*)(xr + kc * 32 + 4);
            float e[8] = {v0.x, v0.y, v0.z, v0.w, v1.x, v1.y, v1.z, v1.w};
            #pragma unroll
            for (int j = 0; j < 8; ++j) {
                _Float16 h = (_Float16)e[j];
                float r = __fsub_rn(e[j], (float)h);
                a_hi[fm][kc][j]  = h;
                a_mid[fm][kc][j] = (_Float16)r;
            }
        }
    }
    float bq[2][4];
    #pragma unroll
    for (int fm = 0; fm < 2; ++fm)
        #pragma unroll
        for (int r = 0; r < 4; ++r)
            bq[fm][r] = bsq[row0 + w_row * 32 + fm * 16 + q * 4 + r];

    // esq -> LDS once (exact copy); epilogue reads hit LDS, not global.
    *(float4*)&esq_lds[tid * 4] = ((const float4*)esq)[tid];

    // Prologue drain doubles as group-0's boundary: my dma_group(0) ops
    // retired + esq published to all waves.
    asm volatile("s_waitcnt vmcnt(0) lgkmcnt(0)" ::: "memory");
    __syncthreads();

    float best[2][4] = {{3.0e38f, 3.0e38f, 3.0e38f, 3.0e38f},
                        {3.0e38f, 3.0e38f, 3.0e38f, 3.0e38f}};
    int bidx[2][4] = {{0, 0, 0, 0}, {0, 0, 0, 0}};

    for (int jt = 0; jt < 8; ++jt) {
        const int j0 = jt * 128;
        f32x4 acc[2][4] = {};
        #pragma unroll
        for (int gi = 0; gi < 4; ++gi) {
            const int g = jt * 4 + gi;
            if (g) {
                // Group boundary: my group-g DMA (issued at top of g-1,
                // ~1 group ago) retired; my g-1 frag reads done (the MFMAs
                // consuming them forced the compiler's lgkm waits, freeing
                // slot (g+1)&1); barrier publishes block-wide.
                asm volatile("s_waitcnt vmcnt(0) lgkmcnt(0)\n\t"
                             "s_barrier" ::: "memory");
            }
            if (g < 31) dma_group(g + 1, (g + 1) & 1);
            const int s = g & 1;
            // Compiler-scheduled from here: plain ds_reads + reg-only MFMAs
            // with automatic fine-grained lgkmcnt -- no manual fences.
            #pragma unroll
            for (int sub = 0; sub < 2; ++sub) {
                const int kc = gi * 2 + sub;
                f16x8 bh[4], bm[4];
                const int fb = sub * 8192 + (w_col * 4) * 512 + lane * 8;
                #pragma unroll
                for (int fn = 0; fn < 4; ++fn) {
                    bh[fn] = *(const f16x8*)&buf[s][fb + fn * 512];
                    bm[fn] = *(const f16x8*)&buf[s][fb + 4096 + fn * 512];
                }
                #pragma unroll
                for (int fm = 0; fm < 2; ++fm)
                    #pragma unroll
                    for (int fn = 0; fn < 4; ++fn) {
                        acc[fm][fn] = __builtin_amdgcn_mfma_f32_16x16x32_f16(
                            a_hi[fm][kc], bh[fn], acc[fm][fn], 0, 0, 0);
                        acc[fm][fn] = __builtin_amdgcn_mfma_f32_16x16x32_f16(
                            a_mid[fm][kc], bh[fn], acc[fm][fn], 0, 0, 0);
                        acc[fm][fn] = __builtin_amdgcn_mfma_f32_16x16x32_f16(
                            a_hi[fm][kc], bm[fn], acc[fm][fn], 0, 0, 0);
                    }
            }
        }
        // Epilogue: reference-rounded d, running argmin (ascending j, strict <)
        // No vmem here (esq/bq/acc in LDS or registers).
        #pragma unroll
        for (int fn = 0; fn < 4; ++fn) {
            const int j = j0 + w_col * 64 + fn * 16 + lm;
            const float eq = esq_lds[j];
            #pragma unroll
            for (int fm = 0; fm < 2; ++fm)
                #pragma unroll
                for (int r = 0; r < 4; ++r) {
                    const float d = __fsub_rn(__fadd_rn(eq, bq[fm][r]),
                                              acc[fm][fn][r] * C_SCALE);
                    if (d < best[fm][r]) { best[fm][r] = d; bidx[fm][r] = j; }
                }
        }
    }
    // Reduce across the 16 col-lanes of each quad (lexicographic min)
    #pragma unroll
    for (int fm = 0; fm < 2; ++fm)
        #pragma unroll
        for (int r = 0; r < 4; ++r) {
            float d = best[fm][r]; int i = bidx[fm][r];
            #pragma unroll
            for (int mv = 1; mv <= 8; mv <<= 1) {
                const float d2 = __shfl_xor(d, mv, 64);
                const int   i2 = __shfl_xor(i, mv, 64);
                if (d2 < d || (d2 == d && i2 < i)) { d = d2; i = i2; }
            }
            best[fm][r] = d; bidx[fm][r] = i;
        }
    __syncthreads();
    if (lm == 0) {
        #pragma unroll
        for (int fm = 0; fm < 2; ++fm)
            #pragma unroll
            for (int r = 0; r < 4; ++r) {
                const int rl = w_row * 32 + fm * 16 + q * 4 + r;
                red_d[rl][w_col] = best[fm][r];
                red_i[rl][w_col] = bidx[fm][r];
            }
    }
    __syncthreads();
    if (tid < 64) {
        float d0 = red_d[tid][0]; int i0 = red_i[tid][0];
        const float d1 = red_d[tid][1]; const int i1 = red_i[tid][1];
        if (d1 < d0 || (d1 == d0 && i1 < i0)) { d0 = d1; i0 = i1; }
        idx_out_f[row0 + tid] = (float)i0;
        idx_out_i[row0 + tid] = i0;
    }
}

// ---------------- kernel 3: gather quantized + commitment loss ------------
__global__ __launch_bounds__(256) void gather_loss_kernel(
    const float4* __restrict__ x4, const float4* __restrict__ emb4,
    const int* __restrict__ idx, float4* __restrict__ q4,
    float* __restrict__ loss_slot) {
    const int base = blockIdx.x * 256 + threadIdx.x;
    float acc = 0.0f;
    #pragma unroll
    for (int i = 0; i < 16; ++i) {
        const int f   = base + i * (1024 * 256);
        const int row = f >> 6;
        const int c4  = f & 63;
        const int e   = idx[row];                  // wave-uniform (64 f4/row)
        float4 qv = emb4[e * D4 + c4];
        float4 xv = x4[f];
        q4[f] = qv;
        const float dx = xv.x - qv.x, dy = xv.y - qv.y;
        const float dz = xv.z - qv.z, dw = xv.w - qv.w;
        acc += dx * dx + dy * dy + dz * dz + dw * dw;
    }
    #pragma unroll
    for (int off = 32; off; off >>= 1) acc += __shfl_down(acc, off, 64);
    __shared__ float wsum[4];
    const int lane = threadIdx.x & 63, w = threadIdx.x >> 6;
    if (lane == 0) wsum[w] = acc;
    __syncthreads();
    if (threadIdx.x == 0) {
        atomicAdd(loss_slot, (wsum[0] + wsum[1] + wsum[2] + wsum[3]) * COMMIT_SCALE);
    }
}

extern "C" void kernel_launch(void* const* d_in, const int* in_sizes, int n_in,
                              void* d_out, int out_size, void* d_ws, size_t ws_size,
                              hipStream_t stream) {
    const float* x   = (const float*)d_in[0];    // 32*2048*256
    const float* emb = (const float*)d_in[1];    // 1024*256
    float* out = (float*)d_out;
    // ws layout (16B-aligned): bsq | esq | idx | e_hi(chunked) | e_mid(chunked)
    float*    bsq  = (float*)d_ws;                       // N_ROWS f32
    float*    esq  = bsq + N_ROWS;                       // M f32
    int*      idx  = (int*)(esq + M);                    // N_ROWS i32
    _Float16* e_hi = (_Float16*)(idx + N_ROWS);          // M*D f16 chunked
    _Float16* e_mid = e_hi + (size_t)M * D;              // M*D f16 chunked

    norms_kernel<<<4096 + M / 16, 256, 0, stream>>>((const float4*)x,
                                                    (const float4*)emb,
                                                    bsq, esq, e_hi, e_mid,
                                                    out + LOSS_OFF);
    argmin_mfma_kernel<<<N_ROWS / 64, 256, 0, stream>>>(x, e_hi, e_mid,
                                                        esq, bsq,
                                                        out + IDX_OFF, idx);
    gather_loss_kernel<<<1024, 256, 0, stream>>>((const float4*)x,
                                                 (const float4*)emb, idx,
                                                 (float4*)out, out + LOSS_OFF);
}

// Round 9
// 225.052 us; speedup vs baseline: 1.0420x; 1.0420x over previous
//
#include <hip/hip_runtime.h>

// Problem constants (fixed by reference setup_inputs)
#define N_ROWS   65536      // 32*2048 flattened rows
#define D        256        // embedding_dim
#define D4       64         // D/4 in float4 units
#define M        1024       // n_embeddings
#define LOSS_OFF 16777216   // d_out offset of loss scalar
#define IDX_OFF  16777217   // d_out offset of indices (as float)
#define COMMIT_SCALE (0.25f / 16777216.0f)  // COMMITMENT_COST / numel(x)
#define E_SCALE  1024.0f    // exact pow2 pre-scale of e so e' in [-1,1]
#define C_SCALE  0.001953125f  // 2/1024: acc*C_SCALE == 2*C exactly

typedef _Float16 f16x8 __attribute__((ext_vector_type(8)));
typedef _Float16 f16x4 __attribute__((ext_vector_type(4)));
typedef float    f32x4 __attribute__((ext_vector_type(4)));

// Async global->LDS DMA, 16 B/lane: LDS dest = base + lane*16 (HW-implicit).
__device__ __forceinline__ void async_copy16(const void* g, void* l) {
    __builtin_amdgcn_global_load_lds(
        (const __attribute__((address_space(1))) unsigned int*)g,
        (__attribute__((address_space(3))) unsigned int*)l, 16, 0, 0);
}

// ===== numpy-exact fp32 row-norm emulation (validated rounds 2-3) =========
__device__ __forceinline__ float np_block128(const float* __restrict__ a, int l) {
    float r0 = __fmul_rn(a[l +   0], a[l +   0]);
    float r1 = __fmul_rn(a[l +  16], a[l +  16]);
    float r2 = __fmul_rn(a[l +  32], a[l +  32]);
    float r3 = __fmul_rn(a[l +  48], a[l +  48]);
    float r4 = __fmul_rn(a[l +  64], a[l +  64]);
    float r5 = __fmul_rn(a[l +  80], a[l +  80]);
    float r6 = __fmul_rn(a[l +  96], a[l +  96]);
    float r7 = __fmul_rn(a[l + 112], a[l + 112]);
    return __fadd_rn(__fadd_rn(__fadd_rn(r0, r1), __fadd_rn(r2, r3)),
                     __fadd_rn(__fadd_rn(r4, r5), __fadd_rn(r6, r7)));
}
__device__ __forceinline__ float np_reduce16(float v) {
    float s = __fadd_rn(v, __shfl_down(v, 8));
    s = __fadd_rn(s, __shfl_down(s, 4));
    s = __fadd_rn(s, __shfl_down(s, 2));
    s = __fadd_rn(s, __shfl_down(s, 1));
    return s;
}

// ------- kernel 1: emb-only np-exact norms + fused e-split (64 blocks) ----
// x-norms moved into the argmin kernel (each block computes bsq for its own
// 64 rows from the same staged data, identical np order -> identical bits).
__global__ __launch_bounds__(256) void emb_kernel(
    const float4* __restrict__ emb4, float* __restrict__ esq,
    _Float16* __restrict__ e_hi, _Float16* __restrict__ e_mid,
    float* __restrict__ loss_slot) {
    __shared__ float rowbuf[16 * 260];   // stride 260: conflict-free np reads
    const int tid = threadIdx.x;
    const int row0 = blockIdx.x * 16;
    const float4* src4 = emb4 + (size_t)row0 * 64;
    #pragma unroll
    for (int p = 0; p < 4; ++p) {
        const int f = tid + p * 256;     // 0..1023 float4s = 16 rows
        const int r = f >> 6, c4 = f & 63;
        *(float4*)&rowbuf[r * 260 + c4 * 4] = src4[f];
    }
    __syncthreads();
    const int l = tid & 15, g = tid >> 4;
    const float* base = &rowbuf[g * 260];
    const float v0 = np_block128(base, l);
    const float v1 = np_block128(base + 128, l);
    const float t0 = np_reduce16(v0);
    const float t1 = np_reduce16(v1);
    if (l == 0) esq[row0 + g] = __fadd_rn(t0, t1);
    if (blockIdx.x == 0 && tid == 0) *loss_slot = 0.0f;  // d_out is poisoned

    // Fused esplit: 4 float4s per thread, values from rowbuf (exact).
    // Layout per (kc, jt) chunk of 8 KB: 16-B granule
    //   g = (code_local>>4)*64 + q*16 + (code_local&15)  -> lane-linear reads
    #pragma unroll
    for (int p = 0; p < 4; ++p) {
        const int f = tid + p * 256;            // block-local float4 id
        const int r = f >> 6, k4 = f & 63;
        const int code = row0 + r;
        const int kc = k4 >> 3, k8 = k4 & 7;    // 32-k chunk, octet pos
        const int q = k8 >> 1, half = k8 & 1;   // k-octet, half-granule
        const int jt = code >> 7, cl = code & 127;
        const int cg = cl >> 4, lmc = cl & 15;
        float4 v = *(const float4*)&rowbuf[r * 260 + k4 * 4];
        float a[4] = {v.x * E_SCALE, v.y * E_SCALE,
                      v.z * E_SCALE, v.w * E_SCALE};
        f16x4 hi, mid;
        #pragma unroll
        for (int j = 0; j < 4; ++j) {
            _Float16 h = (_Float16)a[j];
            float rr = __fsub_rn(a[j], (float)h);
            hi[j] = h;
            mid[j] = (_Float16)rr;
        }
        const size_t ofs = (size_t)kc * 32768 + (size_t)jt * 4096
                         + (size_t)(cg * 64 + q * 16 + lmc) * 8 + half * 4;
        *(f16x4*)&e_hi[ofs]  = hi;
        *(f16x4*)&e_mid[ofs] = mid;
    }
}

// ------------- kernel 2: FULLY FUSED vq kernel (bsq + argmin + gather) ----
// Main loop = r7/r8 structure (2-chunk groups, cooperative dedup'd DMA, one
// fused vmcnt(0)+lgkmcnt(0)+s_barrier per group, compiler-scheduled MFMA
// bursts).  NEW (this round):
//  (a) bsq computed IN-KERNEL: 4 staging rounds of 16 rows through an LDS
//      region aliasing buf[1] (DMA only touches buf[1] after the prologue
//      barrier -> WAR-safe), identical np_block128 order -> identical bits.
//      Also warms L1/L2 for the A-fragment loads that follow.
//  (b) gather+loss FUSED at block tail: final per-row indices kept in LDS;
//      block gathers emb rows (L2-hot), writes q (64 KB/block), accumulates
//      (x-q)^2 and one atomicAdd.  Quantized bytes + indices bit-identical;
//      loss partial ORDER changes (already nondeterministic via atomicAdd
//      completion order across 9 passing rounds -> comparison has tolerance).
// Fragment bytes + MFMA order (hi*bh, mid*bh, hi*bm; fn inner, kc ascending,
// jt ascending) BIT-IDENTICAL to validated rounds.
__global__ __launch_bounds__(256, 2) void vq_kernel(
    const float* __restrict__ x,
    const _Float16* __restrict__ e_hi, const _Float16* __restrict__ e_mid,
    const float* __restrict__ esq, const float4* __restrict__ emb4,
    float4* __restrict__ q4, float* __restrict__ idx_out_f,
    float* __restrict__ loss_slot) {
    // buf[s]: one 2-chunk group: sub*8192 + plane*4096 + data (f16 units);
    // within (sub,plane): granule-permuted chunk half, lane-linear reads.
    __shared__ __attribute__((aligned(16))) _Float16 buf[2][16384];
    __shared__ float esq_lds[1024];
    __shared__ float bsq_lds[64];
    __shared__ int   idx_lds[64];
    __shared__ float red_d[64][2];
    __shared__ int   red_i[64][2];
    __shared__ float wsum[4];

    const int tid = threadIdx.x;
    const int w = tid >> 6, lane = tid & 63;
    const int w_row = w >> 1, w_col = w & 1;
    const int lm = lane & 15, q = lane >> 4;     // A/B frag: [lm][k=q*8+j]
    const int row0 = blockIdx.x * 64;
    const float4* x4 = (const float4*)x;

    // Cooperative group DMA: group g = chunks (jt, kc0) and (jt, kc0+1),
    // 32 KB total.  Wave w moves piece (sub = w>>1, plane = w&1): 8 KB via
    // 8 width-16 ops.  No wave fetches any byte another wave fetches.
    const int p_sub = w >> 1, p_plane = w & 1;
    const _Float16* p_src = p_plane ? e_mid : e_hi;
    auto dma_group = [&](int g, int s) {
        const int jt = g >> 2, kc0 = (g & 3) * 2;
        const char* gp = (const char*)p_src
                       + (size_t)(kc0 + p_sub) * 65536 + (size_t)jt * 8192
                       + (size_t)lane * 16;
        _Float16* lp = &buf[s][p_sub * 8192 + p_plane * 4096];
        #pragma unroll
        for (int u = 0; u < 8; ++u)
            async_copy16(gp + u * 1024, lp + u * 512);
    };

    // Group 0 DMA first: its latency hides under the staging prologue.
    dma_group(0, 0);

    // ---- (a) bsq for this block's 64 rows, np-exact, via LDS staging.
    // Staging region aliases buf[1] (16.6 KB < 32 KB; DMA writes buf[1]
    // only after the prologue barrier below -> no WAR hazard).
    {
        float* rowstage = (float*)&buf[1][0];
        const int l = tid & 15, g16 = tid >> 4;
        #pragma unroll 1
        for (int rr = 0; rr < 4; ++rr) {
            const float4* src4 = x4 + (size_t)(row0 + rr * 16) * 64;
            #pragma unroll
            for (int p = 0; p < 4; ++p) {
                const int f = tid + p * 256;
                const int r = f >> 6, c4 = f & 63;
                *(float4*)&rowstage[r * 260 + c4 * 4] = src4[f];
            }
            __syncthreads();
            const float* base = &rowstage[g16 * 260];
            const float v0 = np_block128(base, l);
            const float v1 = np_block128(base + 128, l);
            const float t0 = np_reduce16(v0);
            const float t1 = np_reduce16(v1);
            if (l == 0) bsq_lds[rr * 16 + g16] = __fadd_rn(t0, t1);
            __syncthreads();
        }
    }

    // ---- A fragments: rows row0 + w_row*32 + fm*16 + lm (L1/L2-hot now)
    f16x8 a_hi[2][8], a_mid[2][8];
    #pragma unroll
    for (int fm = 0; fm < 2; ++fm) {
        const float* xr = x + (size_t)(row0 + w_row * 32 + fm * 16 + lm) * D + q * 8;
        #pragma unroll
        for (int kc = 0; kc < 8; ++kc) {
            float4 v0 = *(const float4*)(xr + kc * 32);
            float4 v1 = *(const float4*)(xr + kc * 32 + 4);
            float e[8] = {v0.x, v0.y, v0.z, v0.w, v1.x, v1.y, v1.z, v1.w};
            #pragma unroll
            for (int j = 0; j < 8; ++j) {
                _Float16 h = (_Float16)e[j];
                float r = __fsub_rn(e[j], (float)h);
                a_hi[fm][kc][j]  = h;
                a_mid[fm][kc][j] = (_Float16)r;
            }
        }
    }
    float bq[2][4];
    #pragma unroll
    for (int fm = 0; fm < 2; ++fm)
        #pragma unroll
        for (int r = 0; r < 4; ++r)
            bq[fm][r] = bsq_lds[w_row * 32 + fm * 16 + q * 4 + r];

    // esq -> LDS once (exact copy); epilogue reads hit LDS, not global.
    *(float4*)&esq_lds[tid * 4] = ((const float4*)esq)[tid];

    // Prologue drain: dma_group(0) retired + esq ds_write done; barrier
    // publishes esq/bsq and frees the staging alias for dma_group(1).
    asm volatile("s_waitcnt vmcnt(0) lgkmcnt(0)" ::: "memory");
    __syncthreads();

    float best[2][4] = {{3.0e38f, 3.0e38f, 3.0e38f, 3.0e38f},
                        {3.0e38f, 3.0e38f, 3.0e38f, 3.0e38f}};
    int bidx[2][4] = {{0, 0, 0, 0}, {0, 0, 0, 0}};

    for (int jt = 0; jt < 8; ++jt) {
        const int j0 = jt * 128;
        f32x4 acc[2][4] = {};
        #pragma unroll
        for (int gi = 0; gi < 4; ++gi) {
            const int g = jt * 4 + gi;
            if (g) {
                // Group boundary: my group-g DMA (issued one group ago)
                // retired; my g-1 frag reads done; barrier publishes.
                asm volatile("s_waitcnt vmcnt(0) lgkmcnt(0)\n\t"
                             "s_barrier" ::: "memory");
            }
            if (g < 31) dma_group(g + 1, (g + 1) & 1);
            const int s = g & 1;
            // Compiler-scheduled: plain ds_reads + reg-only MFMAs with
            // automatic fine-grained lgkmcnt.
            #pragma unroll
            for (int sub = 0; sub < 2; ++sub) {
                const int kc = gi * 2 + sub;
                f16x8 bh[4], bm[4];
                const int fb = sub * 8192 + (w_col * 4) * 512 + lane * 8;
                #pragma unroll
                for (int fn = 0; fn < 4; ++fn) {
                    bh[fn] = *(const f16x8*)&buf[s][fb + fn * 512];
                    bm[fn] = *(const f16x8*)&buf[s][fb + 4096 + fn * 512];
                }
                #pragma unroll
                for (int fm = 0; fm < 2; ++fm)
                    #pragma unroll
                    for (int fn = 0; fn < 4; ++fn) {
                        acc[fm][fn] = __builtin_amdgcn_mfma_f32_16x16x32_f16(
                            a_hi[fm][kc], bh[fn], acc[fm][fn], 0, 0, 0);
                        acc[fm][fn] = __builtin_amdgcn_mfma_f32_16x16x32_f16(
                            a_mid[fm][kc], bh[fn], acc[fm][fn], 0, 0, 0);
                        acc[fm][fn] = __builtin_amdgcn_mfma_f32_16x16x32_f16(
                            a_hi[fm][kc], bm[fn], acc[fm][fn], 0, 0, 0);
                    }
            }
        }
        // Epilogue: reference-rounded d, running argmin (ascending j, strict <)
        #pragma unroll
        for (int fn = 0; fn < 4; ++fn) {
            const int j = j0 + w_col * 64 + fn * 16 + lm;
            const float eq = esq_lds[j];
            #pragma unroll
            for (int fm = 0; fm < 2; ++fm)
                #pragma unroll
                for (int r = 0; r < 4; ++r) {
                    const float d = __fsub_rn(__fadd_rn(eq, bq[fm][r]),
                                              acc[fm][fn][r] * C_SCALE);
                    if (d < best[fm][r]) { best[fm][r] = d; bidx[fm][r] = j; }
                }
        }
    }
    // Reduce across the 16 col-lanes of each quad (lexicographic min)
    #pragma unroll
    for (int fm = 0; fm < 2; ++fm)
        #pragma unroll
        for (int r = 0; r < 4; ++r) {
            float d = best[fm][r]; int i = bidx[fm][r];
            #pragma unroll
            for (int mv = 1; mv <= 8; mv <<= 1) {
                const float d2 = __shfl_xor(d, mv, 64);
                const int   i2 = __shfl_xor(i, mv, 64);
                if (d2 < d || (d2 == d && i2 < i)) { d = d2; i = i2; }
            }
            best[fm][r] = d; bidx[fm][r] = i;
        }
    __syncthreads();
    if (lm == 0) {
        #pragma unroll
        for (int fm = 0; fm < 2; ++fm)
            #pragma unroll
            for (int r = 0; r < 4; ++r) {
                const int rl = w_row * 32 + fm * 16 + q * 4 + r;
                red_d[rl][w_col] = best[fm][r];
                red_i[rl][w_col] = bidx[fm][r];
            }
    }
    __syncthreads();
    if (tid < 64) {
        float d0 = red_d[tid][0]; int i0 = red_i[tid][0];
        const float d1 = red_d[tid][1]; const int i1 = red_i[tid][1];
        if (d1 < d0 || (d1 == d0 && i1 < i0)) { d0 = d1; i0 = i1; }
        idx_out_f[row0 + tid] = (float)i0;
        idx_lds[tid] = i0;
    }
    __syncthreads();

    // ---- (b) fused gather + commitment-loss partial for this block's rows.
    // f spans 64 consecutive float4s per wave -> row (and thus the gathered
    // code) is wave-uniform; emb row is L2-hot; q-write fully coalesced.
    float accl = 0.0f;
    #pragma unroll
    for (int k = 0; k < 16; ++k) {
        const int f = tid + k * 256;              // 0..4095 block-local f4
        const int row = f >> 6, c4 = f & 63;
        const int e = idx_lds[row];
        const size_t gofs = (size_t)(row0 + row) * 64 + c4;
        float4 qv = emb4[e * D4 + c4];
        float4 xv = x4[gofs];
        q4[gofs] = qv;
        const float dx = xv.x - qv.x, dy = xv.y - qv.y;
        const float dz = xv.z - qv.z, dw = xv.w - qv.w;
        accl += dx * dx + dy * dy + dz * dz + dw * dw;
    }
    #pragma unroll
    for (int off = 32; off; off >>= 1) accl += __shfl_down(accl, off, 64);
    if (lane == 0) wsum[w] = accl;
    __syncthreads();
    if (tid == 0)
        atomicAdd(loss_slot,
                  (wsum[0] + wsum[1] + wsum[2] + wsum[3]) * COMMIT_SCALE);
}

extern "C" void kernel_launch(void* const* d_in, const int* in_sizes, int n_in,
                              void* d_out, int out_size, void* d_ws, size_t ws_size,
                              hipStream_t stream) {
    const float* x   = (const float*)d_in[0];    // 32*2048*256
    const float* emb = (const float*)d_in[1];    // 1024*256
    float* out = (float*)d_out;
    // ws layout (16B-aligned): esq | e_hi(chunked) | e_mid(chunked)
    float*    esq  = (float*)d_ws;                       // M f32
    _Float16* e_hi = (_Float16*)(esq + M);               // M*D f16 chunked
    _Float16* e_mid = e_hi + (size_t)M * D;              // M*D f16 chunked

    emb_kernel<<<M / 16, 256, 0, stream>>>((const float4*)emb, esq,
                                           e_hi, e_mid, out + LOSS_OFF);
    vq_kernel<<<N_ROWS / 64, 256, 0, stream>>>(x, e_hi, e_mid, esq,
                                               (const float4*)emb,
                                               (float4*)out, out + IDX_OFF,
                                               out + LOSS_OFF);
}